// Round 5
// baseline (845.882 us; speedup 1.0000x reference)
//
#include <hip/hip_runtime.h>

#define T_STEPS 512
#define F_IN    64
#define HID     20
#define NCLS    10
#define BATCH   1024

__device__ __forceinline__ float rcpf(float x) { return __builtin_amdgcn_rcpf(x); }
__device__ __forceinline__ float bperm(int idxBytes, float v) {
    return __int_as_float(__builtin_amdgcn_ds_bpermute(idxBytes, __float_as_int(v)));
}
__device__ __forceinline__ float rdlane(float v, int lane) {
    return __int_as_float(__builtin_amdgcn_readlane(__float_as_int(v), lane));
}

// ---------------- kernel A: Z0[B*T][80] = x @ W_ih0^T + b0 (round-3 form) ----------------
extern "C" __global__ __launch_bounds__(256)
void zgemm(const float* __restrict__ x, const float* __restrict__ W,
           const float* __restrict__ b0, float* __restrict__ Z)
{
    const size_t row = (size_t)blockIdx.x * 256 + threadIdx.x;
    float xr[F_IN];
    const float4* xp = (const float4*)(x + row * F_IN);
    #pragma unroll
    for (int k = 0; k < F_IN / 4; ++k) ((float4*)xr)[k] = xp[k];

    float* zr = Z + row * 80;
    #pragma unroll 1
    for (int c = 0; c < 80; c += 4) {
        float a0 = b0[c], a1 = b0[c + 1], a2 = b0[c + 2], a3 = b0[c + 3];
        const float* w0 = W + c * F_IN;           // uniform -> s_load
        #pragma unroll
        for (int k = 0; k < F_IN; ++k) {
            a0 = fmaf(w0[k],            xr[k], a0);
            a1 = fmaf(w0[F_IN + k],     xr[k], a1);
            a2 = fmaf(w0[2 * F_IN + k], xr[k], a2);
            a3 = fmaf(w0[3 * F_IN + k], xr[k], a3);
        }
        *(float4*)(zr + c) = make_float4(a0, a1, a2, a3);
    }
}

// ---------------- kernel B: recurrence, 2 batch elems per wave, no barriers ----------------
// lane l: primary gate l (i0-19,f20-39,g40-59,o60-63); lanes&15 also secondary gate 64+(l&15)
// = o[4..19]. h broadcast via readlane -> SGPR; gate gather via precomputed ds_bpermute.
extern "C" __global__ __launch_bounds__(64, 1)
void lstm_rec(const float* __restrict__ Z0,
              const float* __restrict__ W_hh0,
              const float* __restrict__ W_ih1, const float* __restrict__ W_hh1,
              const float* __restrict__ b1,
              const float* __restrict__ W_fc, const float* __restrict__ b_fc,
              float* __restrict__ out)
{
    const int l   = threadIdx.x;
    const int b0i = blockIdx.x * 2;              // elems b0i, b0i+1
    const int g2  = 64 + (l & 15);
    const bool isG = (l >= 40 && l < 60);

    // ---- per-lane weights (shared by both elems) ----
    float wh0p[HID], wh0s[HID], wi1p[HID], wi1s[HID], wh1p[HID], wh1s[HID];
    {
        const float4* p;
        p = (const float4*)(W_hh0 + l  * HID);
        #pragma unroll
        for (int k = 0; k < 5; ++k) ((float4*)wh0p)[k] = p[k];
        p = (const float4*)(W_hh0 + g2 * HID);
        #pragma unroll
        for (int k = 0; k < 5; ++k) ((float4*)wh0s)[k] = p[k];
        p = (const float4*)(W_ih1 + l  * HID);
        #pragma unroll
        for (int k = 0; k < 5; ++k) ((float4*)wi1p)[k] = p[k];
        p = (const float4*)(W_ih1 + g2 * HID);
        #pragma unroll
        for (int k = 0; k < 5; ++k) ((float4*)wi1s)[k] = p[k];
        p = (const float4*)(W_hh1 + l  * HID);
        #pragma unroll
        for (int k = 0; k < 5; ++k) ((float4*)wh1p)[k] = p[k];
        p = (const float4*)(W_hh1 + g2 * HID);
        #pragma unroll
        for (int k = 0; k < 5; ++k) ((float4*)wh1s)[k] = p[k];
    }
    const float b1p = b1[l];
    const float b1s = b1[g2];

    // ---- branchless activation constants ----
    const float mnegP = isG ? -2.885390082f : -1.442695041f;  // -log2e * (2 or 1)
    const float sclP  = isG ? 2.0f : 1.0f;
    const float biaP  = isG ? -1.0f : 0.0f;

    // ---- precomputed bpermute byte-indices ----
    const int idxF  = ((l + 20) & 63) << 2;
    const int idxG  = ((l + 40) & 63) << 2;
    const int idxO  = ((l + 60) & 63) << 2;
    const int idxOB = ((l -  4) & 63) << 2;
    const int cls   = (l < 50) ? (l / 5) : 0;   // FC: class
    const int c4    = (l < 50) ? (l % 5) : 0;   // FC: h-chunk of 4
    const int idxC0 = (c4 * 4 + 0) << 2;
    const int idxC1 = (c4 * 4 + 1) << 2;
    const int idxC2 = (c4 * 4 + 2) << 2;
    const int idxC3 = (c4 * 4 + 3) << 2;

    // ---- streamed-load voffsets (bytes), SGPR base + 32-bit offset ----
    unsigned wfOff = (unsigned)((cls * (T_STEPS * HID) + c4 * 4) * 4);
    unsigned zP0 = (unsigned)(((b0i + 0) * (T_STEPS * 80) + l) * 4);
    unsigned zS0 = (unsigned)(((b0i + 0) * (T_STEPS * 80) + 64 + (l & 15)) * 4);
    unsigned zP1 = (unsigned)(((b0i + 1) * (T_STEPS * 80) + l) * 4);
    unsigned zS1 = (unsigned)(((b0i + 1) * (T_STEPS * 80) + 64 + (l & 15)) * 4);
    const char* Zb  = (const char*)Z0;
    const char* Wfb = (const char*)W_fc;
    #define ZLD(o) (*(const float*)(Zb + (o)))

    // 2-deep z prefetch (cur = t, nxt = t+1); voffsets then point at t+2
    float zpc0 = ZLD(zP0),       zsc0 = ZLD(zS0),       zpc1 = ZLD(zP1),       zsc1 = ZLD(zS1);
    float zpn0 = ZLD(zP0 + 320), zsn0 = ZLD(zS0 + 320), zpn1 = ZLD(zP1 + 320), zsn1 = ZLD(zS1 + 320);
    zP0 += 640; zS0 += 640; zP1 += 640; zS1 += 640;

    // ---- state ----
    float sh0e0[HID], sh1e0[HID], sh0e1[HID], sh1e1[HID];
    #pragma unroll
    for (int j = 0; j < HID; ++j) { sh0e0[j] = 0.f; sh1e0[j] = 0.f; sh0e1[j] = 0.f; sh1e1[j] = 0.f; }
    float c0e0 = 0.f, c1e0 = 0.f, c0e1 = 0.f, c1e1 = 0.f;
    float facc0 = 0.f, facc1 = 0.f;

    for (int t = 0; t < T_STEPS; ++t) {
        const float4 wf = *(const float4*)(Wfb + wfOff);   // W_fc chunk for this t
        wfOff += HID * 4;

        // ---- L0 gate dots (both elems) ----
        float ap00 = zpc0, ap01 = 0.f, as00 = zsc0, as01 = 0.f;
        float ap10 = zpc1, ap11 = 0.f, as10 = zsc1, as11 = 0.f;
        #pragma unroll
        for (int j = 0; j < 10; ++j) {
            ap00 = fmaf(sh0e0[j],      wh0p[j],      ap00);
            ap01 = fmaf(sh0e0[10 + j], wh0p[10 + j], ap01);
            as00 = fmaf(sh0e0[j],      wh0s[j],      as00);
            as01 = fmaf(sh0e0[10 + j], wh0s[10 + j], as01);
            ap10 = fmaf(sh0e1[j],      wh0p[j],      ap10);
            ap11 = fmaf(sh0e1[10 + j], wh0p[10 + j], ap11);
            as10 = fmaf(sh0e1[j],      wh0s[j],      as10);
            as11 = fmaf(sh0e1[10 + j], wh0s[10 + j], as11);
        }
        // rotate z prefetch, issue t+2
        zpc0 = zpn0; zsc0 = zsn0; zpc1 = zpn1; zsc1 = zsn1;
        if (t < T_STEPS - 2) {
            zpn0 = ZLD(zP0); zsn0 = ZLD(zS0); zpn1 = ZLD(zP1); zsn1 = ZLD(zS1);
            zP0 += 320; zS0 += 320; zP1 += 320; zS1 += 320;
        }
        const float actP0 = fmaf(rcpf(1.f + exp2f((ap00 + ap01) * mnegP)), sclP, biaP);
        const float actS0 = rcpf(1.f + exp2f((as00 + as01) * -1.442695041f));
        const float actP1 = fmaf(rcpf(1.f + exp2f((ap10 + ap11) * mnegP)), sclP, biaP);
        const float actS1 = rcpf(1.f + exp2f((as10 + as11) * -1.442695041f));

        // ---- L1 h1-part dots (independent -> fills act/shfl latency) ----
        float bp00 = b1p, bp01 = 0.f, bs00 = b1s, bs01 = 0.f;
        float bp10 = b1p, bp11 = 0.f, bs10 = b1s, bs11 = 0.f;
        #pragma unroll
        for (int j = 0; j < 10; ++j) {
            bp00 = fmaf(sh1e0[j],      wh1p[j],      bp00);
            bp01 = fmaf(sh1e0[10 + j], wh1p[10 + j], bp01);
            bs00 = fmaf(sh1e0[j],      wh1s[j],      bs00);
            bs01 = fmaf(sh1e0[10 + j], wh1s[10 + j], bs01);
            bp10 = fmaf(sh1e1[j],      wh1p[j],      bp10);
            bp11 = fmaf(sh1e1[10 + j], wh1p[10 + j], bp11);
            bs10 = fmaf(sh1e1[j],      wh1s[j],      bs10);
            bs11 = fmaf(sh1e1[10 + j], wh1s[10 + j], bs11);
        }

        // ---- L0 state update e0 ----
        {
            float fv = bperm(idxF, actP0), gv = bperm(idxG, actP0);
            float oA = bperm(idxO, actP0), oB = bperm(idxOB, actS0);
            float ov = (l < 4) ? oA : oB;
            c0e0 = fmaf(fv, c0e0, actP0 * gv);
            float h0 = ov * fmaf(rcpf(1.f + exp2f(c0e0 * -2.885390082f)), 2.f, -1.f);
            #pragma unroll
            for (int j = 0; j < HID; ++j) sh0e0[j] = rdlane(h0, j);
        }
        // ---- L0 state update e1 ----
        {
            float fv = bperm(idxF, actP1), gv = bperm(idxG, actP1);
            float oA = bperm(idxO, actP1), oB = bperm(idxOB, actS1);
            float ov = (l < 4) ? oA : oB;
            c0e1 = fmaf(fv, c0e1, actP1 * gv);
            float h0 = ov * fmaf(rcpf(1.f + exp2f(c0e1 * -2.885390082f)), 2.f, -1.f);
            #pragma unroll
            for (int j = 0; j < HID; ++j) sh0e1[j] = rdlane(h0, j);
        }

        // ---- L1 h0-part dots ----
        #pragma unroll
        for (int j = 0; j < 10; ++j) {
            bp00 = fmaf(sh0e0[j],      wi1p[j],      bp00);
            bp01 = fmaf(sh0e0[10 + j], wi1p[10 + j], bp01);
            bs00 = fmaf(sh0e0[j],      wi1s[j],      bs00);
            bs01 = fmaf(sh0e0[10 + j], wi1s[10 + j], bs01);
            bp10 = fmaf(sh0e1[j],      wi1p[j],      bp10);
            bp11 = fmaf(sh0e1[10 + j], wi1p[10 + j], bp11);
            bs10 = fmaf(sh0e1[j],      wi1s[j],      bs10);
            bs11 = fmaf(sh0e1[10 + j], wi1s[10 + j], bs11);
        }
        const float actQ0 = fmaf(rcpf(1.f + exp2f((bp00 + bp01) * mnegP)), sclP, biaP);
        const float actT0 = rcpf(1.f + exp2f((bs00 + bs01) * -1.442695041f));
        const float actQ1 = fmaf(rcpf(1.f + exp2f((bp10 + bp11) * mnegP)), sclP, biaP);
        const float actT1 = rcpf(1.f + exp2f((bs10 + bs11) * -1.442695041f));

        // ---- L1 state update + FC, e0 ----
        {
            float fv = bperm(idxF, actQ0), gv = bperm(idxG, actQ0);
            float oA = bperm(idxO, actQ0), oB = bperm(idxOB, actT0);
            float ov = (l < 4) ? oA : oB;
            c1e0 = fmaf(fv, c1e0, actQ0 * gv);
            float h1 = ov * fmaf(rcpf(1.f + exp2f(c1e0 * -2.885390082f)), 2.f, -1.f);
            #pragma unroll
            for (int j = 0; j < HID; ++j) sh1e0[j] = rdlane(h1, j);
            facc0 = fmaf(bperm(idxC0, h1), wf.x, facc0);
            facc0 = fmaf(bperm(idxC1, h1), wf.y, facc0);
            facc0 = fmaf(bperm(idxC2, h1), wf.z, facc0);
            facc0 = fmaf(bperm(idxC3, h1), wf.w, facc0);
        }
        // ---- L1 state update + FC, e1 ----
        {
            float fv = bperm(idxF, actQ1), gv = bperm(idxG, actQ1);
            float oA = bperm(idxO, actQ1), oB = bperm(idxOB, actT1);
            float ov = (l < 4) ? oA : oB;
            c1e1 = fmaf(fv, c1e1, actQ1 * gv);
            float h1 = ov * fmaf(rcpf(1.f + exp2f(c1e1 * -2.885390082f)), 2.f, -1.f);
            #pragma unroll
            for (int j = 0; j < HID; ++j) sh1e1[j] = rdlane(h1, j);
            facc1 = fmaf(bperm(idxC0, h1), wf.x, facc1);
            facc1 = fmaf(bperm(idxC1, h1), wf.y, facc1);
            facc1 = fmaf(bperm(idxC2, h1), wf.z, facc1);
            facc1 = fmaf(bperm(idxC3, h1), wf.w, facc1);
        }
    }

    // ---- epilogue: reduce FC partials over the 5 chunk-lanes per class ----
    float r0 = facc0, r1 = facc1;
    r0 += __shfl(facc0, l + 1); r1 += __shfl(facc1, l + 1);
    r0 += __shfl(facc0, l + 2); r1 += __shfl(facc1, l + 2);
    r0 += __shfl(facc0, l + 3); r1 += __shfl(facc1, l + 3);
    r0 += __shfl(facc0, l + 4); r1 += __shfl(facc1, l + 4);
    if (l < 50 && (l % 5) == 0) {
        const int cc = l / 5;
        const float bb = b_fc[cc];
        out[(size_t)(b0i + 0) * NCLS + cc] = r0 + bb;
        out[(size_t)(b0i + 1) * NCLS + cc] = r1 + bb;
    }
}

extern "C" void kernel_launch(void* const* d_in, const int* in_sizes, int n_in,
                              void* d_out, int out_size, void* d_ws, size_t ws_size,
                              hipStream_t stream) {
    const float* x     = (const float*)d_in[0];
    const float* W_ih0 = (const float*)d_in[1];
    const float* W_hh0 = (const float*)d_in[2];
    const float* b0    = (const float*)d_in[3];
    const float* W_ih1 = (const float*)d_in[4];
    const float* W_hh1 = (const float*)d_in[5];
    const float* b1    = (const float*)d_in[6];
    const float* W_fc  = (const float*)d_in[7];
    const float* b_fc  = (const float*)d_in[8];
    float* out = (float*)d_out;

    float* Z0 = (float*)d_ws;   // B*T*80*4 = 167.8 MB workspace

    const int rows = BATCH * T_STEPS;                       // 524288
    zgemm<<<dim3(rows / 256), dim3(256), 0, stream>>>(x, W_ih0, b0, Z0);
    lstm_rec<<<dim3(BATCH / 2), dim3(64), 0, stream>>>(Z0, W_hh0, W_ih1, W_hh1,
                                                       b1, W_fc, b_fc, out);
}

// Round 6
// 563.473 us; speedup vs baseline: 1.5012x; 1.5012x over previous
//
#include <hip/hip_runtime.h>

#define T_STEPS 512
#define F_IN    64
#define HID     20
#define NCLS    10
#define BATCH   1024

__device__ __forceinline__ float rcpf(float x) { return __builtin_amdgcn_rcpf(x); }
__device__ __forceinline__ float bperm(int idxBytes, float v) {
    return __int_as_float(__builtin_amdgcn_ds_bpermute(idxBytes, __float_as_int(v)));
}
__device__ __forceinline__ float rdlane(float v, int lane) {
    return __int_as_float(__builtin_amdgcn_readlane(__float_as_int(v), lane));
}

// ---------------- kernel A: Z0[B*T][80] = x @ W_ih0^T + b0 ----------------
// one row/thread; weights wave-uniform -> s_load; 8-col groups to amortize waits
extern "C" __global__ __launch_bounds__(256)
void zgemm(const float* __restrict__ x, const float* __restrict__ W,
           const float* __restrict__ b0, float* __restrict__ Z)
{
    const size_t row = (size_t)blockIdx.x * 256 + threadIdx.x;
    float xr[F_IN];
    const float4* xp = (const float4*)(x + row * F_IN);
    #pragma unroll
    for (int k = 0; k < F_IN / 4; ++k) ((float4*)xr)[k] = xp[k];

    float* zr = Z + row * 80;
    #pragma unroll 1
    for (int c = 0; c < 80; c += 8) {
        float a0 = b0[c],     a1 = b0[c + 1], a2 = b0[c + 2], a3 = b0[c + 3];
        float a4 = b0[c + 4], a5 = b0[c + 5], a6 = b0[c + 6], a7 = b0[c + 7];
        const float* w0 = W + c * F_IN;       // uniform -> s_load
        #pragma unroll
        for (int k = 0; k < F_IN; ++k) {
            const float xv = xr[k];
            a0 = fmaf(w0[k],             xv, a0);
            a1 = fmaf(w0[F_IN + k],      xv, a1);
            a2 = fmaf(w0[2 * F_IN + k],  xv, a2);
            a3 = fmaf(w0[3 * F_IN + k],  xv, a3);
            a4 = fmaf(w0[4 * F_IN + k],  xv, a4);
            a5 = fmaf(w0[5 * F_IN + k],  xv, a5);
            a6 = fmaf(w0[6 * F_IN + k],  xv, a6);
            a7 = fmaf(w0[7 * F_IN + k],  xv, a7);
        }
        *(float4*)(zr + c)     = make_float4(a0, a1, a2, a3);
        *(float4*)(zr + c + 4) = make_float4(a4, a5, a6, a7);
    }
}

// ---------------- kernel B: layer-pipelined recurrence ----------------
// block = 1 batch elem, 2 waves. wave0: layer0 (lane=gate p/s, h0 -> LDS ring).
// wave1: layer1+FC, one step behind, h0 via uniform ds_read broadcast.
// 1024 blocks x 2 waves = 2048 waves = 2 waves/SIMD -> mutual stall filling.
extern "C" __global__ __launch_bounds__(128, 2)
void lstm_rec(const float* __restrict__ Z0,
              const float* __restrict__ W_hh0,
              const float* __restrict__ W_ih1, const float* __restrict__ W_hh1,
              const float* __restrict__ b1,
              const float* __restrict__ W_fc, const float* __restrict__ b_fc,
              float* __restrict__ out)
{
    __shared__ float ring[2][24];            // h0 handoff, 2 slots

    const int tid = threadIdx.x;
    const int l   = tid & 63;
    const int wid = tid >> 6;                // 0 = layer0, 1 = layer1+FC
    const int b   = blockIdx.x;
    const int g2  = 64 + (l & 15);           // secondary gate = o[4..19]
    const bool isG = (l >= 40 && l < 60);

    const float mnegP = isG ? -2.885390082f : -1.442695041f;
    const float sclP  = isG ? 2.0f : 1.0f;
    const float biaP  = isG ? -1.0f : 0.0f;

    const int idxF  = ((l + 20) & 63) << 2;
    const int idxG  = ((l + 40) & 63) << 2;
    const int idxO  = ((l + 60) & 63) << 2;
    const int idxOB = ((l -  4) & 63) << 2;

    // ---------------- wave-0 state ----------------
    float wh0p[HID], wh0s[HID];
    float sh0[HID];
    float c0 = 0.f;
    float zpc = 0.f, zsc = 0.f, zpn = 0.f, zsn = 0.f;
    unsigned zP = 0, zS = 0;
    const char* Zb = (const char*)Z0;
    #define ZLD(o) (*(const float*)(Zb + (o)))

    // ---------------- wave-1 state ----------------
    float wi1p[HID], wi1s[HID], wh1p[HID], wh1s[HID];
    float sh1[HID];
    float b1p = 0.f, b1s = 0.f;
    float c1 = 0.f, facc = 0.f;
    unsigned wfOff = 0;
    int idxC0 = 0, idxC1 = 0, idxC2 = 0, idxC3 = 0;
    const char* Wfb = (const char*)W_fc;

    if (wid == 0) {
        const float4* p;
        p = (const float4*)(W_hh0 + l  * HID);
        #pragma unroll
        for (int k = 0; k < 5; ++k) ((float4*)wh0p)[k] = p[k];
        p = (const float4*)(W_hh0 + g2 * HID);
        #pragma unroll
        for (int k = 0; k < 5; ++k) ((float4*)wh0s)[k] = p[k];
        #pragma unroll
        for (int j = 0; j < HID; ++j) sh0[j] = 0.f;

        zP = (unsigned)((b * (T_STEPS * 80) + l) * 4);
        zS = (unsigned)((b * (T_STEPS * 80) + 64 + (l & 15)) * 4);
        zpc = ZLD(zP);       zsc = ZLD(zS);
        zpn = ZLD(zP + 320); zsn = ZLD(zS + 320);
        zP += 640; zS += 640;
    } else {
        const float4* p;
        p = (const float4*)(W_ih1 + l  * HID);
        #pragma unroll
        for (int k = 0; k < 5; ++k) ((float4*)wi1p)[k] = p[k];
        p = (const float4*)(W_ih1 + g2 * HID);
        #pragma unroll
        for (int k = 0; k < 5; ++k) ((float4*)wi1s)[k] = p[k];
        p = (const float4*)(W_hh1 + l  * HID);
        #pragma unroll
        for (int k = 0; k < 5; ++k) ((float4*)wh1p)[k] = p[k];
        p = (const float4*)(W_hh1 + g2 * HID);
        #pragma unroll
        for (int k = 0; k < 5; ++k) ((float4*)wh1s)[k] = p[k];
        b1p = b1[l];
        b1s = b1[g2];
        #pragma unroll
        for (int j = 0; j < HID; ++j) sh1[j] = 0.f;

        const int cls = (l < 50) ? (l / 5) : 0;
        const int c4  = (l < 50) ? (l % 5) : 0;
        idxC0 = (c4 * 4 + 0) << 2;
        idxC1 = (c4 * 4 + 1) << 2;
        idxC2 = (c4 * 4 + 2) << 2;
        idxC3 = (c4 * 4 + 3) << 2;
        wfOff = (unsigned)((cls * (T_STEPS * HID) + c4 * 4) * 4);
    }

    // ---- layer1 + FC step for logical time tau (wave1 only) ----
    auto l1_step = [&](int tau) {
        // issue streamed loads first (consumed late)
        const float4 wf = *(const float4*)(Wfb + wfOff);
        wfOff += HID * 4;
        float h0u[HID];
        {
            const float4* rp = (const float4*)(&ring[tau & 1][0]);
            ((float4*)h0u)[0] = rp[0];
            ((float4*)h0u)[1] = rp[1];
            ((float4*)h0u)[2] = rp[2];
            ((float4*)h0u)[3] = rp[3];
            ((float4*)h0u)[4] = rp[4];
        }
        // h1-part dots (no LDS dependency -> overlaps ds_read latency)
        float bp0 = b1p, bp1 = 0.f, bs0 = b1s, bs1 = 0.f;
        #pragma unroll
        for (int j = 0; j < 10; ++j) {
            bp0 = fmaf(sh1[j],      wh1p[j],      bp0);
            bp1 = fmaf(sh1[10 + j], wh1p[10 + j], bp1);
            bs0 = fmaf(sh1[j],      wh1s[j],      bs0);
            bs1 = fmaf(sh1[10 + j], wh1s[10 + j], bs1);
        }
        // h0-part dots
        #pragma unroll
        for (int j = 0; j < 10; ++j) {
            bp0 = fmaf(h0u[j],      wi1p[j],      bp0);
            bp1 = fmaf(h0u[10 + j], wi1p[10 + j], bp1);
            bs0 = fmaf(h0u[j],      wi1s[j],      bs0);
            bs1 = fmaf(h0u[10 + j], wi1s[10 + j], bs1);
        }
        const float actQ = fmaf(rcpf(1.f + exp2f((bp0 + bp1) * mnegP)), sclP, biaP);
        const float actT = rcpf(1.f + exp2f((bs0 + bs1) * -1.442695041f));
        const float fv = bperm(idxF, actQ), gv = bperm(idxG, actQ);
        const float oA = bperm(idxO, actQ), oB = bperm(idxOB, actT);
        const float ov = (l < 4) ? oA : oB;
        c1 = fmaf(fv, c1, actQ * gv);
        const float h1v = ov * fmaf(rcpf(1.f + exp2f(c1 * -2.885390082f)), 2.f, -1.f);
        #pragma unroll
        for (int j = 0; j < HID; ++j) sh1[j] = rdlane(h1v, j);
        facc = fmaf(bperm(idxC0, h1v), wf.x, facc);
        facc = fmaf(bperm(idxC1, h1v), wf.y, facc);
        facc = fmaf(bperm(idxC2, h1v), wf.z, facc);
        facc = fmaf(bperm(idxC3, h1v), wf.w, facc);
    };

    for (int t = 0; t < T_STEPS; ++t) {
        if (wid == 0) {
            // ---- layer0 gates for step t ----
            float ap0 = zpc, ap1 = 0.f, as0 = zsc, as1 = 0.f;
            #pragma unroll
            for (int j = 0; j < 10; ++j) {
                ap0 = fmaf(sh0[j],      wh0p[j],      ap0);
                ap1 = fmaf(sh0[10 + j], wh0p[10 + j], ap1);
                as0 = fmaf(sh0[j],      wh0s[j],      as0);
                as1 = fmaf(sh0[10 + j], wh0s[10 + j], as1);
            }
            // rotate z prefetch, issue t+2
            zpc = zpn; zsc = zsn;
            if (t < T_STEPS - 2) {
                zpn = ZLD(zP); zsn = ZLD(zS);
                zP += 320; zS += 320;
            }
            const float actP = fmaf(rcpf(1.f + exp2f((ap0 + ap1) * mnegP)), sclP, biaP);
            const float actS = rcpf(1.f + exp2f((as0 + as1) * -1.442695041f));
            const float fv = bperm(idxF, actP), gv = bperm(idxG, actP);
            const float oA = bperm(idxO, actP), oB = bperm(idxOB, actS);
            const float ov = (l < 4) ? oA : oB;
            c0 = fmaf(fv, c0, actP * gv);
            const float h0v = ov * fmaf(rcpf(1.f + exp2f(c0 * -2.885390082f)), 2.f, -1.f);
            #pragma unroll
            for (int j = 0; j < HID; ++j) sh0[j] = rdlane(h0v, j);
            if (l < HID) ring[t & 1][l] = h0v;       // publish h0(t)
        } else {
            if (t > 0) l1_step(t - 1);               // consume h0(t-1)
        }
        __syncthreads();                             // convergent, 2-wave barrier
    }

    // epilogue: wave1 finishes tau = T-1 and stores
    if (wid == 1) {
        l1_step(T_STEPS - 1);
        float r = facc;
        r += __shfl(facc, l + 1);
        r += __shfl(facc, l + 2);
        r += __shfl(facc, l + 3);
        r += __shfl(facc, l + 4);
        if (l < 50 && (l % 5) == 0)
            out[(size_t)b * NCLS + (l / 5)] = r + b_fc[l / 5];
    }
}

extern "C" void kernel_launch(void* const* d_in, const int* in_sizes, int n_in,
                              void* d_out, int out_size, void* d_ws, size_t ws_size,
                              hipStream_t stream) {
    const float* x     = (const float*)d_in[0];
    const float* W_ih0 = (const float*)d_in[1];
    const float* W_hh0 = (const float*)d_in[2];
    const float* b0    = (const float*)d_in[3];
    const float* W_ih1 = (const float*)d_in[4];
    const float* W_hh1 = (const float*)d_in[5];
    const float* b1    = (const float*)d_in[6];
    const float* W_fc  = (const float*)d_in[7];
    const float* b_fc  = (const float*)d_in[8];
    float* out = (float*)d_out;

    float* Z0 = (float*)d_ws;   // B*T*80*4 = 167.8 MB workspace

    const int rows = BATCH * T_STEPS;                       // 524288
    zgemm<<<dim3(rows / 256), dim3(256), 0, stream>>>(x, W_ih0, b0, Z0);
    lstm_rec<<<dim3(BATCH), dim3(128), 0, stream>>>(Z0, W_hh0, W_ih1, W_hh1,
                                                    b1, W_fc, b_fc, out);
}

// Round 7
// 455.879 us; speedup vs baseline: 1.8555x; 1.2360x over previous
//
#include <hip/hip_runtime.h>

#define T_STEPS 512
#define F_IN    64
#define HID     20
#define NCLS    10
#define BATCH   1024

__device__ __forceinline__ float rcpf(float x) { return __builtin_amdgcn_rcpf(x); }
__device__ __forceinline__ float bperm(int idxBytes, float v) {
    return __int_as_float(__builtin_amdgcn_ds_bpermute(idxBytes, __float_as_int(v)));
}

// ---------------- kernel A: Z0[B*T][80] = x @ W_ih0^T + b0 ----------------
extern "C" __global__ __launch_bounds__(256)
void zgemm(const float* __restrict__ x, const float* __restrict__ W,
           const float* __restrict__ b0, float* __restrict__ Z)
{
    const size_t row = (size_t)blockIdx.x * 256 + threadIdx.x;
    float xr[F_IN];
    const float4* xp = (const float4*)(x + row * F_IN);
    #pragma unroll
    for (int k = 0; k < F_IN / 4; ++k) ((float4*)xr)[k] = xp[k];

    float* zr = Z + row * 80;
    #pragma unroll 1
    for (int c = 0; c < 80; c += 8) {
        float a0 = b0[c],     a1 = b0[c + 1], a2 = b0[c + 2], a3 = b0[c + 3];
        float a4 = b0[c + 4], a5 = b0[c + 5], a6 = b0[c + 6], a7 = b0[c + 7];
        const float* w0 = W + c * F_IN;       // uniform -> s_load
        #pragma unroll
        for (int k = 0; k < F_IN; ++k) {
            const float xv = xr[k];
            a0 = fmaf(w0[k],             xv, a0);
            a1 = fmaf(w0[F_IN + k],      xv, a1);
            a2 = fmaf(w0[2 * F_IN + k],  xv, a2);
            a3 = fmaf(w0[3 * F_IN + k],  xv, a3);
            a4 = fmaf(w0[4 * F_IN + k],  xv, a4);
            a5 = fmaf(w0[5 * F_IN + k],  xv, a5);
            a6 = fmaf(w0[6 * F_IN + k],  xv, a6);
            a7 = fmaf(w0[7 * F_IN + k],  xv, a7);
        }
        *(float4*)(zr + c)     = make_float4(a0, a1, a2, a3);
        *(float4*)(zr + c + 4) = make_float4(a4, a5, a6, a7);
    }
}

// ---------------- kernel B: layer-pipelined recurrence, LDS h-rings ----------------
// block = 1 elem, 2 waves. wave0: layer0 (t) + FC (t-4). wave1: layer1 (t-2).
// h0 ring: 4 slots; h1 ring: 8 slots. barrier every 2 steps; slot arithmetic keeps
// intra-interval reads/writes disjoint. All h broadcasts = uniform ds_read_b128.
extern "C" __global__ __launch_bounds__(128, 2)
void lstm_rec(const float* __restrict__ Z0,
              const float* __restrict__ W_hh0,
              const float* __restrict__ W_ih1, const float* __restrict__ W_hh1,
              const float* __restrict__ b1,
              const float* __restrict__ W_fc, const float* __restrict__ b_fc,
              float* __restrict__ out)
{
    __shared__ float4 ringH0v[4][6];     // [slot][24 floats]
    __shared__ float4 ringH1v[8][6];
    float* ringH0 = (float*)ringH0v;
    float* ringH1 = (float*)ringH1v;

    const int tid = threadIdx.x;
    const int l   = tid & 63;
    const int wid = tid >> 6;            // 0 = layer0+FC, 1 = layer1
    const int b   = blockIdx.x;
    const int g2  = 64 + (l & 15);       // secondary gate = o[4..19]
    const bool isG = (l >= 40 && l < 60);

    const float mnegP = isG ? -2.885390082f : -1.442695041f;
    const float sclP  = isG ? 2.0f : 1.0f;
    const float biaP  = isG ? -1.0f : 0.0f;

    const int idxF  = ((l + 20) & 63) << 2;
    const int idxG  = ((l + 40) & 63) << 2;
    const int idxO  = ((l + 60) & 63) << 2;
    const int idxOB = ((l -  4) & 63) << 2;

    // zero rings
    for (int i = tid; i < 96; i += 128)  ringH0[i] = 0.f;
    for (int i = tid; i < 192; i += 128) ringH1[i] = 0.f;

    // ---------------- wave-0 state ----------------
    float wh0p[HID], wh0s[HID];
    float c0 = 0.f;
    float zpc = 0.f, zsc = 0.f, zpn = 0.f, zsn = 0.f;
    unsigned zP = 0, zS = 0;
    const char* Zb = (const char*)Z0;
    #define ZLD(o) (*(const float*)(Zb + (o)))
    // FC state (wave0)
    float fa = 0.f, fb = 0.f;
    unsigned wfOff = 0;
    int c4off = 0;
    const char* Wfb = (const char*)W_fc;

    // ---------------- wave-1 state ----------------
    float wi1p[HID], wi1s[HID], wh1p[HID], wh1s[HID];
    float b1p = 0.f, b1s = 0.f;
    float c1 = 0.f;

    if (wid == 0) {
        const float4* p;
        p = (const float4*)(W_hh0 + l  * HID);
        #pragma unroll
        for (int k = 0; k < 5; ++k) ((float4*)wh0p)[k] = p[k];
        p = (const float4*)(W_hh0 + g2 * HID);
        #pragma unroll
        for (int k = 0; k < 5; ++k) ((float4*)wh0s)[k] = p[k];

        zP = (unsigned)((b * (T_STEPS * 80) + l) * 4);
        zS = (unsigned)((b * (T_STEPS * 80) + 64 + (l & 15)) * 4);
        zpc = ZLD(zP);       zsc = ZLD(zS);
        zpn = ZLD(zP + 320); zsn = ZLD(zS + 320);
        zP += 640; zS += 640;

        const int cls = (l < 50) ? (l / 5) : 0;
        const int c4  = (l < 50) ? (l % 5) : 0;
        c4off = c4 * 16;                                  // byte offset into h1 slot
        wfOff = (unsigned)((cls * (T_STEPS * HID) + c4 * 4) * 4);
    } else {
        const float4* p;
        p = (const float4*)(W_ih1 + l  * HID);
        #pragma unroll
        for (int k = 0; k < 5; ++k) ((float4*)wi1p)[k] = p[k];
        p = (const float4*)(W_ih1 + g2 * HID);
        #pragma unroll
        for (int k = 0; k < 5; ++k) ((float4*)wi1s)[k] = p[k];
        p = (const float4*)(W_hh1 + l  * HID);
        #pragma unroll
        for (int k = 0; k < 5; ++k) ((float4*)wh1p)[k] = p[k];
        p = (const float4*)(W_hh1 + g2 * HID);
        #pragma unroll
        for (int k = 0; k < 5; ++k) ((float4*)wh1s)[k] = p[k];
        b1p = b1[l];
        b1s = b1[g2];
    }
    __syncthreads();

    for (int t = 0; t < T_STEPS + 4; ++t) {
        if (wid == 0) {
            // ---- early streamed loads ----
            const int sigma = t - 4;                      // FC step
            float4 wf = make_float4(0.f, 0.f, 0.f, 0.f);
            if (sigma >= 0) {
                wf = *(const float4*)(Wfb + wfOff);
                wfOff += HID * 4;
            }
            if (t < T_STEPS) {
                const float zp = zpc, zs = zsc;
                zpc = zpn; zsc = zsn;
                if (t + 2 < T_STEPS) {                    // issue t+2 at step top
                    zpn = ZLD(zP); zsn = ZLD(zS);
                    zP += 320; zS += 320;
                }
                // h0(t-1) via uniform LDS broadcast
                float h0u[HID];
                {
                    const float4* hp = (const float4*)(ringH0 + ((t + 3) & 3) * 24);
                    #pragma unroll
                    for (int k = 0; k < 5; ++k) ((float4*)h0u)[k] = hp[k];
                }
                float ap0 = zp, ap1 = 0.f, as0 = zs, as1 = 0.f;
                #pragma unroll
                for (int j = 0; j < 10; ++j) {
                    ap0 = fmaf(h0u[j],      wh0p[j],      ap0);
                    ap1 = fmaf(h0u[10 + j], wh0p[10 + j], ap1);
                    as0 = fmaf(h0u[j],      wh0s[j],      as0);
                    as1 = fmaf(h0u[10 + j], wh0s[10 + j], as1);
                }
                const float actP = fmaf(rcpf(1.f + exp2f((ap0 + ap1) * mnegP)), sclP, biaP);
                const float actS = rcpf(1.f + exp2f((as0 + as1) * -1.442695041f));
                const float fv = bperm(idxF, actP), gv = bperm(idxG, actP);
                const float oA = bperm(idxO, actP), oB = bperm(idxOB, actS);
                const float ov = (l < 4) ? oA : oB;
                c0 = fmaf(fv, c0, actP * gv);
                const float h0v = ov * fmaf(rcpf(1.f + exp2f(c0 * -2.885390082f)), 2.f, -1.f);
                if (l < HID) ringH0[(t & 3) * 24 + l] = h0v;
            }
            // ---- FC for sigma (h1 published >=1 barrier ago) ----
            if (sigma >= 0) {
                const float4 h1q = *(const float4*)((const char*)ringH1 +
                                                    ((sigma & 7) * 96) + c4off);
                fa = fmaf(h1q.x, wf.x, fa);
                fb = fmaf(h1q.y, wf.y, fb);
                fa = fmaf(h1q.z, wf.z, fa);
                fb = fmaf(h1q.w, wf.w, fb);
            }
        } else {
            const int tau = t - 2;                        // layer1 step
            if (tau >= 0 && tau < T_STEPS) {
                float h0u[HID], h1u[HID];
                {
                    const float4* hp = (const float4*)(ringH0 + (tau & 3) * 24);
                    #pragma unroll
                    for (int k = 0; k < 5; ++k) ((float4*)h0u)[k] = hp[k];
                    const float4* hq = (const float4*)(ringH1 + ((tau + 7) & 7) * 24);
                    #pragma unroll
                    for (int k = 0; k < 5; ++k) ((float4*)h1u)[k] = hq[k];
                }
                float bp0 = b1p, bp1 = 0.f, bs0 = b1s, bs1 = 0.f;
                #pragma unroll
                for (int j = 0; j < 10; ++j) {
                    bp0 = fmaf(h1u[j],      wh1p[j],      bp0);
                    bp1 = fmaf(h1u[10 + j], wh1p[10 + j], bp1);
                    bs0 = fmaf(h1u[j],      wh1s[j],      bs0);
                    bs1 = fmaf(h1u[10 + j], wh1s[10 + j], bs1);
                }
                #pragma unroll
                for (int j = 0; j < 10; ++j) {
                    bp0 = fmaf(h0u[j],      wi1p[j],      bp0);
                    bp1 = fmaf(h0u[10 + j], wi1p[10 + j], bp1);
                    bs0 = fmaf(h0u[j],      wi1s[j],      bs0);
                    bs1 = fmaf(h0u[10 + j], wi1s[10 + j], bs1);
                }
                const float actQ = fmaf(rcpf(1.f + exp2f((bp0 + bp1) * mnegP)), sclP, biaP);
                const float actT = rcpf(1.f + exp2f((bs0 + bs1) * -1.442695041f));
                const float fv = bperm(idxF, actQ), gv = bperm(idxG, actQ);
                const float oA = bperm(idxO, actQ), oB = bperm(idxOB, actT);
                const float ov = (l < 4) ? oA : oB;
                c1 = fmaf(fv, c1, actQ * gv);
                const float h1v = ov * fmaf(rcpf(1.f + exp2f(c1 * -2.885390082f)), 2.f, -1.f);
                if (l < HID) ringH1[(tau & 7) * 24 + l] = h1v;
            }
        }
        if (t & 1) __syncthreads();                       // barrier per 2 steps
    }

    // ---- epilogue: wave0 reduces FC partials (5 chunk lanes per class) ----
    if (wid == 0) {
        const float f = fa + fb;
        float r = f;
        r += __shfl(f, l + 1);
        r += __shfl(f, l + 2);
        r += __shfl(f, l + 3);
        r += __shfl(f, l + 4);
        if (l < 50 && (l % 5) == 0)
            out[(size_t)b * NCLS + (l / 5)] = r + b_fc[l / 5];
    }
}

extern "C" void kernel_launch(void* const* d_in, const int* in_sizes, int n_in,
                              void* d_out, int out_size, void* d_ws, size_t ws_size,
                              hipStream_t stream) {
    const float* x     = (const float*)d_in[0];
    const float* W_ih0 = (const float*)d_in[1];
    const float* W_hh0 = (const float*)d_in[2];
    const float* b0    = (const float*)d_in[3];
    const float* W_ih1 = (const float*)d_in[4];
    const float* W_hh1 = (const float*)d_in[5];
    const float* b1    = (const float*)d_in[6];
    const float* W_fc  = (const float*)d_in[7];
    const float* b_fc  = (const float*)d_in[8];
    float* out = (float*)d_out;

    float* Z0 = (float*)d_ws;   // B*T*80*4 = 167.8 MB workspace

    const int rows = BATCH * T_STEPS;                       // 524288
    zgemm<<<dim3(rows / 256), dim3(256), 0, stream>>>(x, W_ih0, b0, Z0);
    lstm_rec<<<dim3(BATCH), dim3(128), 0, stream>>>(Z0, W_hh0, W_ih1, W_hh1,
                                                    b1, W_fc, b_fc, out);
}

// Round 8
// 367.136 us; speedup vs baseline: 2.3040x; 1.2417x over previous
//
#include <hip/hip_runtime.h>

#define T_STEPS 512
#define F_IN    64
#define HID     20
#define NCLS    10
#define BATCH   1024

typedef __attribute__((ext_vector_type(8))) short bf16x8;   // MFMA A/B operand
typedef __attribute__((ext_vector_type(4))) float f32x4;    // MFMA C/D operand

__device__ __forceinline__ float rcpf(float x) { return __builtin_amdgcn_rcpf(x); }
__device__ __forceinline__ float bperm(int idxBytes, float v) {
    return __int_as_float(__builtin_amdgcn_ds_bpermute(idxBytes, __float_as_int(v)));
}
__device__ __forceinline__ unsigned short bf16h(float v) {  // fp32 -> bf16 bits, RNE
    unsigned u = __float_as_uint(v);
    return (unsigned short)((u + 0x7fffu + ((u >> 16) & 1u)) >> 16);
}
__device__ __forceinline__ float bf16f(unsigned short h) {  // bf16 bits -> fp32
    return __uint_as_float(((unsigned)h) << 16);
}

// ---------------- kernel A: Z0 = x @ W_ih0^T + b0, split-bf16 MFMA ----------------
// wave = 32 rows x 80 cols, one-shot. x tile: fp32 coalesced -> hi/lo bf16 planes in
// LDS (pad 72 ushorts) -> ds_read_b128 A-frags. W-frags direct global (L2-hot).
// 3 passes: hi*hi + hi*lo + lo*hi  (lo*lo ~2^-18 dropped).
extern "C" __global__ __launch_bounds__(256, 2)
void zgemm_mfma(const float* __restrict__ x, const float* __restrict__ W,
                const float* __restrict__ b0, float* __restrict__ Z)
{
    __shared__ unsigned short xlds[4][2][32][72];   // [wave][plane][row][k], 36 KB

    const int tid = threadIdx.x;
    const int w   = tid >> 6;
    const int l   = tid & 63;
    const int ar  = l & 15;          // frag row/col within 16
    const int aq  = l >> 4;          // frag quarter
    const size_t R0 = ((size_t)blockIdx.x * 4 + w) * 32;

    // ---- stage x tile: coalesced fp32 loads -> hi/lo bf16 planes ----
    const float* xw = x + R0 * F_IN;
    #pragma unroll
    for (int i = 0; i < 8; ++i) {
        const int idx = (i << 6) + l;            // 0..511 float4 slots
        const int row = idx >> 4;
        const int c4  = idx & 15;
        const float4 v = *(const float4*)(xw + (row << 6) + (c4 << 2));
        const unsigned short h0 = bf16h(v.x), h1 = bf16h(v.y),
                             h2 = bf16h(v.z), h3 = bf16h(v.w);
        const unsigned short g0 = bf16h(v.x - bf16f(h0)), g1 = bf16h(v.y - bf16f(h1)),
                             g2 = bf16h(v.z - bf16f(h2)), g3 = bf16h(v.w - bf16f(h3));
        *(uint2*)&xlds[w][0][row][c4 << 2] =
            make_uint2((unsigned)h0 | ((unsigned)h1 << 16), (unsigned)h2 | ((unsigned)h3 << 16));
        *(uint2*)&xlds[w][1][row][c4 << 2] =
            make_uint2((unsigned)g0 | ((unsigned)g1 << 16), (unsigned)g2 | ((unsigned)g3 << 16));
    }
    __syncthreads();

    // ---- A fragments: lane holds row (l&15), k-chunk (l>>4)*8 + s*32 ----
    bf16x8 af[2][2][2];                          // [m][s][plane]
    #pragma unroll
    for (int m = 0; m < 2; ++m)
        #pragma unroll
        for (int s = 0; s < 2; ++s) {
            af[m][s][0] = *(const bf16x8*)&xlds[w][0][m * 16 + ar][aq * 8 + s * 32];
            af[m][s][1] = *(const bf16x8*)&xlds[w][1][m * 16 + ar][aq * 8 + s * 32];
        }

    // ---- B fragments from global W (same 20 KB for all waves -> L2 broadcast) ----
    bf16x8 bfr[5][2][2];                         // [n][s][plane]
    #pragma unroll
    for (int n = 0; n < 5; ++n)
        #pragma unroll
        for (int s = 0; s < 2; ++s) {
            const float* wp = W + (size_t)(n * 16 + ar) * F_IN + aq * 8 + s * 32;
            const float4 u = *(const float4*)wp;
            const float4 v = *(const float4*)(wp + 4);
            bf16x8 hf, gf;
            hf[0] = (short)bf16h(u.x); gf[0] = (short)bf16h(u.x - bf16f(bf16h(u.x)));
            hf[1] = (short)bf16h(u.y); gf[1] = (short)bf16h(u.y - bf16f(bf16h(u.y)));
            hf[2] = (short)bf16h(u.z); gf[2] = (short)bf16h(u.z - bf16f(bf16h(u.z)));
            hf[3] = (short)bf16h(u.w); gf[3] = (short)bf16h(u.w - bf16f(bf16h(u.w)));
            hf[4] = (short)bf16h(v.x); gf[4] = (short)bf16h(v.x - bf16f(bf16h(v.x)));
            hf[5] = (short)bf16h(v.y); gf[5] = (short)bf16h(v.y - bf16f(bf16h(v.y)));
            hf[6] = (short)bf16h(v.z); gf[6] = (short)bf16h(v.z - bf16f(bf16h(v.z)));
            hf[7] = (short)bf16h(v.w); gf[7] = (short)bf16h(v.w - bf16f(bf16h(v.w)));
            bfr[n][s][0] = hf;
            bfr[n][s][1] = gf;
        }

    // ---- 60 MFMAs + store ----
    #pragma unroll
    for (int m = 0; m < 2; ++m)
        #pragma unroll
        for (int n = 0; n < 5; ++n) {
            const float bb = b0[n * 16 + ar];
            f32x4 acc = {bb, bb, bb, bb};
            #pragma unroll
            for (int s = 0; s < 2; ++s) {
                acc = __builtin_amdgcn_mfma_f32_16x16x32_bf16(af[m][s][0], bfr[n][s][0], acc, 0, 0, 0);
                acc = __builtin_amdgcn_mfma_f32_16x16x32_bf16(af[m][s][0], bfr[n][s][1], acc, 0, 0, 0);
                acc = __builtin_amdgcn_mfma_f32_16x16x32_bf16(af[m][s][1], bfr[n][s][0], acc, 0, 0, 0);
            }
            // C/D: col = l&15, row = (l>>4)*4 + reg   [verified m89 layout]
            float* zp = Z + (R0 + m * 16 + aq * 4) * 80 + n * 16 + ar;
            zp[0]   = acc[0];
            zp[80]  = acc[1];
            zp[160] = acc[2];
            zp[240] = acc[3];
        }
}

// ---------------- kernel B: layer-pipelined recurrence, LDS h-rings (round-7, unchanged) ----------------
extern "C" __global__ __launch_bounds__(128, 2)
void lstm_rec(const float* __restrict__ Z0,
              const float* __restrict__ W_hh0,
              const float* __restrict__ W_ih1, const float* __restrict__ W_hh1,
              const float* __restrict__ b1,
              const float* __restrict__ W_fc, const float* __restrict__ b_fc,
              float* __restrict__ out)
{
    __shared__ float4 ringH0v[4][6];     // [slot][24 floats]
    __shared__ float4 ringH1v[8][6];
    float* ringH0 = (float*)ringH0v;
    float* ringH1 = (float*)ringH1v;

    const int tid = threadIdx.x;
    const int l   = tid & 63;
    const int wid = tid >> 6;            // 0 = layer0+FC, 1 = layer1
    const int b   = blockIdx.x;
    const int g2  = 64 + (l & 15);       // secondary gate = o[4..19]
    const bool isG = (l >= 40 && l < 60);

    const float mnegP = isG ? -2.885390082f : -1.442695041f;
    const float sclP  = isG ? 2.0f : 1.0f;
    const float biaP  = isG ? -1.0f : 0.0f;

    const int idxF  = ((l + 20) & 63) << 2;
    const int idxG  = ((l + 40) & 63) << 2;
    const int idxO  = ((l + 60) & 63) << 2;
    const int idxOB = ((l -  4) & 63) << 2;

    for (int i = tid; i < 96; i += 128)  ringH0[i] = 0.f;
    for (int i = tid; i < 192; i += 128) ringH1[i] = 0.f;

    float wh0p[HID], wh0s[HID];
    float c0 = 0.f;
    float zpc = 0.f, zsc = 0.f, zpn = 0.f, zsn = 0.f;
    unsigned zP = 0, zS = 0;
    const char* Zb = (const char*)Z0;
    #define ZLD(o) (*(const float*)(Zb + (o)))
    float fa = 0.f, fb = 0.f;
    unsigned wfOff = 0;
    int c4off = 0;
    const char* Wfb = (const char*)W_fc;

    float wi1p[HID], wi1s[HID], wh1p[HID], wh1s[HID];
    float b1p = 0.f, b1s = 0.f;
    float c1 = 0.f;

    if (wid == 0) {
        const float4* p;
        p = (const float4*)(W_hh0 + l  * HID);
        #pragma unroll
        for (int k = 0; k < 5; ++k) ((float4*)wh0p)[k] = p[k];
        p = (const float4*)(W_hh0 + g2 * HID);
        #pragma unroll
        for (int k = 0; k < 5; ++k) ((float4*)wh0s)[k] = p[k];

        zP = (unsigned)((b * (T_STEPS * 80) + l) * 4);
        zS = (unsigned)((b * (T_STEPS * 80) + 64 + (l & 15)) * 4);
        zpc = ZLD(zP);       zsc = ZLD(zS);
        zpn = ZLD(zP + 320); zsn = ZLD(zS + 320);
        zP += 640; zS += 640;

        const int cls = (l < 50) ? (l / 5) : 0;
        const int c4  = (l < 50) ? (l % 5) : 0;
        c4off = c4 * 16;
        wfOff = (unsigned)((cls * (T_STEPS * HID) + c4 * 4) * 4);
    } else {
        const float4* p;
        p = (const float4*)(W_ih1 + l  * HID);
        #pragma unroll
        for (int k = 0; k < 5; ++k) ((float4*)wi1p)[k] = p[k];
        p = (const float4*)(W_ih1 + g2 * HID);
        #pragma unroll
        for (int k = 0; k < 5; ++k) ((float4*)wi1s)[k] = p[k];
        p = (const float4*)(W_hh1 + l  * HID);
        #pragma unroll
        for (int k = 0; k < 5; ++k) ((float4*)wh1p)[k] = p[k];
        p = (const float4*)(W_hh1 + g2 * HID);
        #pragma unroll
        for (int k = 0; k < 5; ++k) ((float4*)wh1s)[k] = p[k];
        b1p = b1[l];
        b1s = b1[g2];
    }
    __syncthreads();

    for (int t = 0; t < T_STEPS + 4; ++t) {
        if (wid == 0) {
            const int sigma = t - 4;
            float4 wf = make_float4(0.f, 0.f, 0.f, 0.f);
            if (sigma >= 0) {
                wf = *(const float4*)(Wfb + wfOff);
                wfOff += HID * 4;
            }
            if (t < T_STEPS) {
                const float zp = zpc, zs = zsc;
                zpc = zpn; zsc = zsn;
                if (t + 2 < T_STEPS) {
                    zpn = ZLD(zP); zsn = ZLD(zS);
                    zP += 320; zS += 320;
                }
                float h0u[HID];
                {
                    const float4* hp = (const float4*)(ringH0 + ((t + 3) & 3) * 24);
                    #pragma unroll
                    for (int k = 0; k < 5; ++k) ((float4*)h0u)[k] = hp[k];
                }
                float ap0 = zp, ap1 = 0.f, as0 = zs, as1 = 0.f;
                #pragma unroll
                for (int j = 0; j < 10; ++j) {
                    ap0 = fmaf(h0u[j],      wh0p[j],      ap0);
                    ap1 = fmaf(h0u[10 + j], wh0p[10 + j], ap1);
                    as0 = fmaf(h0u[j],      wh0s[j],      as0);
                    as1 = fmaf(h0u[10 + j], wh0s[10 + j], as1);
                }
                const float actP = fmaf(rcpf(1.f + exp2f((ap0 + ap1) * mnegP)), sclP, biaP);
                const float actS = rcpf(1.f + exp2f((as0 + as1) * -1.442695041f));
                const float fv = bperm(idxF, actP), gv = bperm(idxG, actP);
                const float oA = bperm(idxO, actP), oB = bperm(idxOB, actS);
                const float ov = (l < 4) ? oA : oB;
                c0 = fmaf(fv, c0, actP * gv);
                const float h0v = ov * fmaf(rcpf(1.f + exp2f(c0 * -2.885390082f)), 2.f, -1.f);
                if (l < HID) ringH0[(t & 3) * 24 + l] = h0v;
            }
            if (sigma >= 0) {
                const float4 h1q = *(const float4*)((const char*)ringH1 +
                                                    ((sigma & 7) * 96) + c4off);
                fa = fmaf(h1q.x, wf.x, fa);
                fb = fmaf(h1q.y, wf.y, fb);
                fa = fmaf(h1q.z, wf.z, fa);
                fb = fmaf(h1q.w, wf.w, fb);
            }
        } else {
            const int tau = t - 2;
            if (tau >= 0 && tau < T_STEPS) {
                float h0u[HID], h1u[HID];
                {
                    const float4* hp = (const float4*)(ringH0 + (tau & 3) * 24);
                    #pragma unroll
                    for (int k = 0; k < 5; ++k) ((float4*)h0u)[k] = hp[k];
                    const float4* hq = (const float4*)(ringH1 + ((tau + 7) & 7) * 24);
                    #pragma unroll
                    for (int k = 0; k < 5; ++k) ((float4*)h1u)[k] = hq[k];
                }
                float bp0 = b1p, bp1 = 0.f, bs0 = b1s, bs1 = 0.f;
                #pragma unroll
                for (int j = 0; j < 10; ++j) {
                    bp0 = fmaf(h1u[j],      wh1p[j],      bp0);
                    bp1 = fmaf(h1u[10 + j], wh1p[10 + j], bp1);
                    bs0 = fmaf(h1u[j],      wh1s[j],      bs0);
                    bs1 = fmaf(h1u[10 + j], wh1s[10 + j], bs1);
                }
                #pragma unroll
                for (int j = 0; j < 10; ++j) {
                    bp0 = fmaf(h0u[j],      wi1p[j],      bp0);
                    bp1 = fmaf(h0u[10 + j], wi1p[10 + j], bp1);
                    bs0 = fmaf(h0u[j],      wi1s[j],      bs0);
                    bs1 = fmaf(h0u[10 + j], wi1s[10 + j], bs1);
                }
                const float actQ = fmaf(rcpf(1.f + exp2f((bp0 + bp1) * mnegP)), sclP, biaP);
                const float actT = rcpf(1.f + exp2f((bs0 + bs1) * -1.442695041f));
                const float fv = bperm(idxF, actQ), gv = bperm(idxG, actQ);
                const float oA = bperm(idxO, actQ), oB = bperm(idxOB, actT);
                const float ov = (l < 4) ? oA : oB;
                c1 = fmaf(fv, c1, actQ * gv);
                const float h1v = ov * fmaf(rcpf(1.f + exp2f(c1 * -2.885390082f)), 2.f, -1.f);
                if (l < HID) ringH1[(tau & 7) * 24 + l] = h1v;
            }
        }
        if (t & 1) __syncthreads();
    }

    if (wid == 0) {
        const float f = fa + fb;
        float r = f;
        r += __shfl(f, l + 1);
        r += __shfl(f, l + 2);
        r += __shfl(f, l + 3);
        r += __shfl(f, l + 4);
        if (l < 50 && (l % 5) == 0)
            out[(size_t)b * NCLS + (l / 5)] = r + b_fc[l / 5];
    }
}

extern "C" void kernel_launch(void* const* d_in, const int* in_sizes, int n_in,
                              void* d_out, int out_size, void* d_ws, size_t ws_size,
                              hipStream_t stream) {
    const float* x     = (const float*)d_in[0];
    const float* W_ih0 = (const float*)d_in[1];
    const float* W_hh0 = (const float*)d_in[2];
    const float* b0    = (const float*)d_in[3];
    const float* W_ih1 = (const float*)d_in[4];
    const float* W_hh1 = (const float*)d_in[5];
    const float* b1    = (const float*)d_in[6];
    const float* W_fc  = (const float*)d_in[7];
    const float* b_fc  = (const float*)d_in[8];
    float* out = (float*)d_out;

    float* Z0 = (float*)d_ws;   // B*T*80*4 = 167.8 MB workspace

    zgemm_mfma<<<dim3(4096), dim3(256), 0, stream>>>(x, W_ih0, b0, Z0);
    lstm_rec<<<dim3(BATCH), dim3(128), 0, stream>>>(Z0, W_hh0, W_ih1, W_hh1,
                                                    b1, W_fc, b_fc, out);
}

// Round 9
// 316.752 us; speedup vs baseline: 2.6705x; 1.1591x over previous
//
#include <hip/hip_runtime.h>

#define T_STEPS 512
#define F_IN    64
#define HID     20
#define NCLS    10
#define BATCH   1024

typedef __attribute__((ext_vector_type(8))) short bf16x8;   // MFMA A/B operand
typedef __attribute__((ext_vector_type(4))) float f32x4;    // MFMA C/D operand
typedef __attribute__((ext_vector_type(2))) float f32x2;

__device__ __forceinline__ float rcpf(float x) { return __builtin_amdgcn_rcpf(x); }
__device__ __forceinline__ float bperm(int idxBytes, float v) {
    return __int_as_float(__builtin_amdgcn_ds_bpermute(idxBytes, __float_as_int(v)));
}
__device__ __forceinline__ unsigned short bf16h(float v) {  // fp32 -> bf16 bits, RNE
    unsigned u = __float_as_uint(v);
    return (unsigned short)((u + 0x7fffu + ((u >> 16) & 1u)) >> 16);
}
__device__ __forceinline__ float bf16f(unsigned short h) {  // bf16 bits -> fp32
    return __uint_as_float(((unsigned)h) << 16);
}
// packed fp32 FMA: d = a*b + c on both halves (the 157 TF fp32 path)
__device__ __forceinline__ f32x2 pkfma(f32x2 a, f32x2 b, f32x2 c) {
    f32x2 d;
    asm("v_pk_fma_f32 %0, %1, %2, %3" : "=v"(d) : "v"(a), "v"(b), "v"(c));
    return d;
}

// ---------------- kernel A: Z0 = x @ W_ih0^T + b0, split-bf16 MFMA (round-8, unchanged) ----------------
extern "C" __global__ __launch_bounds__(256, 2)
void zgemm_mfma(const float* __restrict__ x, const float* __restrict__ W,
                const float* __restrict__ b0, float* __restrict__ Z)
{
    __shared__ unsigned short xlds[4][2][32][72];   // [wave][plane][row][k], 36 KB

    const int tid = threadIdx.x;
    const int w   = tid >> 6;
    const int l   = tid & 63;
    const int ar  = l & 15;
    const int aq  = l >> 4;
    const size_t R0 = ((size_t)blockIdx.x * 4 + w) * 32;

    const float* xw = x + R0 * F_IN;
    #pragma unroll
    for (int i = 0; i < 8; ++i) {
        const int idx = (i << 6) + l;
        const int row = idx >> 4;
        const int c4  = idx & 15;
        const float4 v = *(const float4*)(xw + (row << 6) + (c4 << 2));
        const unsigned short h0 = bf16h(v.x), h1 = bf16h(v.y),
                             h2 = bf16h(v.z), h3 = bf16h(v.w);
        const unsigned short g0 = bf16h(v.x - bf16f(h0)), g1 = bf16h(v.y - bf16f(h1)),
                             g2 = bf16h(v.z - bf16f(h2)), g3 = bf16h(v.w - bf16f(h3));
        *(uint2*)&xlds[w][0][row][c4 << 2] =
            make_uint2((unsigned)h0 | ((unsigned)h1 << 16), (unsigned)h2 | ((unsigned)h3 << 16));
        *(uint2*)&xlds[w][1][row][c4 << 2] =
            make_uint2((unsigned)g0 | ((unsigned)g1 << 16), (unsigned)g2 | ((unsigned)g3 << 16));
    }
    __syncthreads();

    bf16x8 af[2][2][2];
    #pragma unroll
    for (int m = 0; m < 2; ++m)
        #pragma unroll
        for (int s = 0; s < 2; ++s) {
            af[m][s][0] = *(const bf16x8*)&xlds[w][0][m * 16 + ar][aq * 8 + s * 32];
            af[m][s][1] = *(const bf16x8*)&xlds[w][1][m * 16 + ar][aq * 8 + s * 32];
        }

    bf16x8 bfr[5][2][2];
    #pragma unroll
    for (int n = 0; n < 5; ++n)
        #pragma unroll
        for (int s = 0; s < 2; ++s) {
            const float* wp = W + (size_t)(n * 16 + ar) * F_IN + aq * 8 + s * 32;
            const float4 u = *(const float4*)wp;
            const float4 v = *(const float4*)(wp + 4);
            bf16x8 hf, gf;
            hf[0] = (short)bf16h(u.x); gf[0] = (short)bf16h(u.x - bf16f(bf16h(u.x)));
            hf[1] = (short)bf16h(u.y); gf[1] = (short)bf16h(u.y - bf16f(bf16h(u.y)));
            hf[2] = (short)bf16h(u.z); gf[2] = (short)bf16h(u.z - bf16f(bf16h(u.z)));
            hf[3] = (short)bf16h(u.w); gf[3] = (short)bf16h(u.w - bf16f(bf16h(u.w)));
            hf[4] = (short)bf16h(v.x); gf[4] = (short)bf16h(v.x - bf16f(bf16h(v.x)));
            hf[5] = (short)bf16h(v.y); gf[5] = (short)bf16h(v.y - bf16f(bf16h(v.y)));
            hf[6] = (short)bf16h(v.z); gf[6] = (short)bf16h(v.z - bf16f(bf16h(v.z)));
            hf[7] = (short)bf16h(v.w); gf[7] = (short)bf16h(v.w - bf16f(bf16h(v.w)));
            bfr[n][s][0] = hf;
            bfr[n][s][1] = gf;
        }

    #pragma unroll
    for (int m = 0; m < 2; ++m)
        #pragma unroll
        for (int n = 0; n < 5; ++n) {
            const float bb = b0[n * 16 + ar];
            f32x4 acc = {bb, bb, bb, bb};
            #pragma unroll
            for (int s = 0; s < 2; ++s) {
                acc = __builtin_amdgcn_mfma_f32_16x16x32_bf16(af[m][s][0], bfr[n][s][0], acc, 0, 0, 0);
                acc = __builtin_amdgcn_mfma_f32_16x16x32_bf16(af[m][s][0], bfr[n][s][1], acc, 0, 0, 0);
                acc = __builtin_amdgcn_mfma_f32_16x16x32_bf16(af[m][s][1], bfr[n][s][0], acc, 0, 0, 0);
            }
            float* zp = Z + (R0 + m * 16 + aq * 4) * 80 + n * 16 + ar;
            zp[0]   = acc[0];
            zp[80]  = acc[1];
            zp[160] = acc[2];
            zp[240] = acc[3];
        }
}

// ---------------- kernel B: layer-pipelined recurrence, pk_fma dots, unroll-8 ----------------
// block = 1 elem, 2 waves. wave0: layer0 (t) + FC (t-4). wave1: layer1 (t-2).
// h rings in LDS; all broadcasts uniform ds_read_b128; #pragma unroll 8 makes all
// ring-slot indices compile-time constants (t known mod 8).
extern "C" __global__ __launch_bounds__(128, 2)
void lstm_rec(const float* __restrict__ Z0,
              const float* __restrict__ W_hh0,
              const float* __restrict__ W_ih1, const float* __restrict__ W_hh1,
              const float* __restrict__ b1,
              const float* __restrict__ W_fc, const float* __restrict__ b_fc,
              float* __restrict__ out)
{
    __shared__ float4 ringH0v[4][6];     // [slot][24 floats]
    __shared__ float4 ringH1v[8][6];
    float* ringH0 = (float*)ringH0v;
    float* ringH1 = (float*)ringH1v;

    const int tid = threadIdx.x;
    const int l   = tid & 63;
    const int wid = tid >> 6;            // 0 = layer0+FC, 1 = layer1
    const int b   = blockIdx.x;
    const int g2  = 64 + (l & 15);       // secondary gate = o[4..19]
    const bool isG = (l >= 40 && l < 60);

    const float mnegP = isG ? -2.885390082f : -1.442695041f;
    const float sclP  = isG ? 2.0f : 1.0f;
    const float biaP  = isG ? -1.0f : 0.0f;

    const int idxF  = ((l + 20) & 63) << 2;
    const int idxG  = ((l + 40) & 63) << 2;
    const int idxO  = ((l + 60) & 63) << 2;
    const int idxOB = ((l -  4) & 63) << 2;

    for (int i = tid; i < 96; i += 128)  ringH0[i] = 0.f;
    for (int i = tid; i < 192; i += 128) ringH1[i] = 0.f;

    // ---------------- wave-0 state ----------------
    f32x2 wh0p2[10], wh0s2[10];
    float c0 = 0.f;
    float zpc = 0.f, zsc = 0.f, zpn = 0.f, zsn = 0.f;
    unsigned zP = 0, zS = 0;
    const char* Zb = (const char*)Z0;
    #define ZLD(o) (*(const float*)(Zb + (o)))
    f32x2 facc2 = {0.f, 0.f};
    unsigned wfOff = 0;
    int c4off = 0;
    const char* Wfb = (const char*)W_fc;

    // ---------------- wave-1 state ----------------
    f32x2 wi1p2[10], wi1s2[10], wh1p2[10], wh1s2[10];
    float b1p = 0.f, b1s = 0.f;
    float c1 = 0.f;

    if (wid == 0) {
        const f32x2* p;
        p = (const f32x2*)(W_hh0 + l  * HID);
        #pragma unroll
        for (int k = 0; k < 10; ++k) wh0p2[k] = p[k];
        p = (const f32x2*)(W_hh0 + g2 * HID);
        #pragma unroll
        for (int k = 0; k < 10; ++k) wh0s2[k] = p[k];

        zP = (unsigned)((b * (T_STEPS * 80) + l) * 4);
        zS = (unsigned)((b * (T_STEPS * 80) + 64 + (l & 15)) * 4);
        zpc = ZLD(zP);       zsc = ZLD(zS);
        zpn = ZLD(zP + 320); zsn = ZLD(zS + 320);
        zP += 640; zS += 640;

        const int cls = (l < 50) ? (l / 5) : 0;
        const int c4  = (l < 50) ? (l % 5) : 0;
        c4off = c4 * 16;
        wfOff = (unsigned)((cls * (T_STEPS * HID) + c4 * 4) * 4);
    } else {
        const f32x2* p;
        p = (const f32x2*)(W_ih1 + l  * HID);
        #pragma unroll
        for (int k = 0; k < 10; ++k) wi1p2[k] = p[k];
        p = (const f32x2*)(W_ih1 + g2 * HID);
        #pragma unroll
        for (int k = 0; k < 10; ++k) wi1s2[k] = p[k];
        p = (const f32x2*)(W_hh1 + l  * HID);
        #pragma unroll
        for (int k = 0; k < 10; ++k) wh1p2[k] = p[k];
        p = (const f32x2*)(W_hh1 + g2 * HID);
        #pragma unroll
        for (int k = 0; k < 10; ++k) wh1s2[k] = p[k];
        b1p = b1[l];
        b1s = b1[g2];
    }
    __syncthreads();

    #pragma unroll 8
    for (int t = 0; t < T_STEPS + 4; ++t) {
        if (wid == 0) {
            const int sigma = t - 4;
            float4 wf = make_float4(0.f, 0.f, 0.f, 0.f);
            if (sigma >= 0) {
                wf = *(const float4*)(Wfb + wfOff);
                wfOff += HID * 4;
            }
            if (t < T_STEPS) {
                const float zp = zpc, zs = zsc;
                zpc = zpn; zsc = zsn;
                if (t + 2 < T_STEPS) {
                    zpn = ZLD(zP); zsn = ZLD(zS);
                    zP += 320; zS += 320;
                }
                // h0(t-1) broadcast: 5 uniform ds_read_b128 -> 10 f32x2
                f32x2 h2[10];
                {
                    const f32x4* hp = (const f32x4*)(ringH0 + ((t + 3) & 3) * 24);
                    #pragma unroll
                    for (int k = 0; k < 5; ++k) {
                        const f32x4 v = hp[k];
                        h2[2 * k]     = __builtin_shufflevector(v, v, 0, 1);
                        h2[2 * k + 1] = __builtin_shufflevector(v, v, 2, 3);
                    }
                }
                f32x2 aP = {zp, 0.f}, aP1 = {0.f, 0.f};
                f32x2 aS = {zs, 0.f}, aS1 = {0.f, 0.f};
                #pragma unroll
                for (int j = 0; j < 5; ++j) {
                    aP  = pkfma(h2[j],     wh0p2[j],     aP);
                    aP1 = pkfma(h2[5 + j], wh0p2[5 + j], aP1);
                    aS  = pkfma(h2[j],     wh0s2[j],     aS);
                    aS1 = pkfma(h2[5 + j], wh0s2[5 + j], aS1);
                }
                const float a_p = (aP.x + aP1.x) + (aP.y + aP1.y);
                const float a_s = (aS.x + aS1.x) + (aS.y + aS1.y);
                const float actP = fmaf(rcpf(1.f + exp2f(a_p * mnegP)), sclP, biaP);
                const float actS = rcpf(1.f + exp2f(a_s * -1.442695041f));
                const float fv = bperm(idxF, actP), gv = bperm(idxG, actP);
                const float oA = bperm(idxO, actP), oB = bperm(idxOB, actS);
                const float ov = (l < 4) ? oA : oB;
                c0 = fmaf(fv, c0, actP * gv);
                const float h0v = ov * fmaf(rcpf(1.f + exp2f(c0 * -2.885390082f)), 2.f, -1.f);
                if (l < HID) ringH0[(t & 3) * 24 + l] = h0v;
            }
            if (sigma >= 0) {
                const float4 h1q = *(const float4*)((const char*)ringH1 +
                                                    ((sigma & 7) * 96) + c4off);
                facc2 = pkfma((f32x2){h1q.x, h1q.y}, (f32x2){wf.x, wf.y}, facc2);
                facc2 = pkfma((f32x2){h1q.z, h1q.w}, (f32x2){wf.z, wf.w}, facc2);
            }
        } else {
            const int tau = t - 2;
            if (tau >= 0 && tau < T_STEPS) {
                f32x2 h02[10], h12[10];
                {
                    const f32x4* hp = (const f32x4*)(ringH0 + (tau & 3) * 24);
                    const f32x4* hq = (const f32x4*)(ringH1 + ((tau + 7) & 7) * 24);
                    #pragma unroll
                    for (int k = 0; k < 5; ++k) {
                        const f32x4 v = hp[k];
                        const f32x4 u = hq[k];
                        h02[2 * k]     = __builtin_shufflevector(v, v, 0, 1);
                        h02[2 * k + 1] = __builtin_shufflevector(v, v, 2, 3);
                        h12[2 * k]     = __builtin_shufflevector(u, u, 0, 1);
                        h12[2 * k + 1] = __builtin_shufflevector(u, u, 2, 3);
                    }
                }
                f32x2 bP = {b1p, 0.f}, bP1 = {0.f, 0.f};
                f32x2 bS = {b1s, 0.f}, bS1 = {0.f, 0.f};
                #pragma unroll
                for (int j = 0; j < 5; ++j) {
                    bP  = pkfma(h12[j],     wh1p2[j],     bP);
                    bP1 = pkfma(h12[5 + j], wh1p2[5 + j], bP1);
                    bS  = pkfma(h12[j],     wh1s2[j],     bS);
                    bS1 = pkfma(h12[5 + j], wh1s2[5 + j], bS1);
                }
                #pragma unroll
                for (int j = 0; j < 5; ++j) {
                    bP  = pkfma(h02[j],     wi1p2[j],     bP);
                    bP1 = pkfma(h02[5 + j], wi1p2[5 + j], bP1);
                    bS  = pkfma(h02[j],     wi1s2[j],     bS);
                    bS1 = pkfma(h02[5 + j], wi1s2[5 + j], bS1);
                }
                const float b_p = (bP.x + bP1.x) + (bP.y + bP1.y);
                const float b_s = (bS.x + bS1.x) + (bS.y + bS1.y);
                const float actQ = fmaf(rcpf(1.f + exp2f(b_p * mnegP)), sclP, biaP);
                const float actT = rcpf(1.f + exp2f(b_s * -1.442695041f));
                const float fv = bperm(idxF, actQ), gv = bperm(idxG, actQ);
                const float oA = bperm(idxO, actQ), oB = bperm(idxOB, actT);
                const float ov = (l < 4) ? oA : oB;
                c1 = fmaf(fv, c1, actQ * gv);
                const float h1v = ov * fmaf(rcpf(1.f + exp2f(c1 * -2.885390082f)), 2.f, -1.f);
                if (l < HID) ringH1[(tau & 7) * 24 + l] = h1v;
            }
        }
        if (t & 1) __syncthreads();
    }

    if (wid == 0) {
        const float f = facc2.x + facc2.y;
        float r = f;
        r += __shfl(f, l + 1);
        r += __shfl(f, l + 2);
        r += __shfl(f, l + 3);
        r += __shfl(f, l + 4);
        if (l < 50 && (l % 5) == 0)
            out[(size_t)b * NCLS + (l / 5)] = r + b_fc[l / 5];
    }
}

extern "C" void kernel_launch(void* const* d_in, const int* in_sizes, int n_in,
                              void* d_out, int out_size, void* d_ws, size_t ws_size,
                              hipStream_t stream) {
    const float* x     = (const float*)d_in[0];
    const float* W_ih0 = (const float*)d_in[1];
    const float* W_hh0 = (const float*)d_in[2];
    const float* b0    = (const float*)d_in[3];
    const float* W_ih1 = (const float*)d_in[4];
    const float* W_hh1 = (const float*)d_in[5];
    const float* b1    = (const float*)d_in[6];
    const float* W_fc  = (const float*)d_in[7];
    const float* b_fc  = (const float*)d_in[8];
    float* out = (float*)d_out;

    float* Z0 = (float*)d_ws;   // B*T*80*4 = 167.8 MB workspace

    zgemm_mfma<<<dim3(4096), dim3(256), 0, stream>>>(x, W_ih0, b0, Z0);
    lstm_rec<<<dim3(BATCH), dim3(128), 0, stream>>>(Z0, W_hh0, W_ih1, W_hh1,
                                                    b1, W_fc, b_fc, out);
}